// Round 4
// baseline (351.158 us; speedup 1.0000x reference)
//
#include <hip/hip_runtime.h>

// Problem constants (fixed by the reference file)
constexpr int C = 32;
constexpr int H = 128;
constexpr int W = 512;
constexpr int PAD = 40;
constexpr int D = PAD + 1;     // 41 disparity planes
constexpr int W4 = W / 4;      // 128 float4 per row
constexpr int HW4 = H * W4;    // float4s per (c,d) plane

// Native vector type usable with __builtin_nontemporal_store
typedef float f32x4 __attribute__((ext_vector_type(4)));

// out[c][d][h][w] = (w >= d) ? in1[c][h][w] * in2[c][h][w-d] : 0
//
// One workgroup per (c, h-pair): 256 threads = 2 rows x 128 float4 slots.
// in2 row staged in LDS once; in1 float4 kept in a register.
// d-loop: outer j (NOT unrolled -> ~2 live float4s, no VGPR spill),
// inner rr=0..3 compile-time sub-planes sharing one cur/prev LDS pair.
__global__ __launch_bounds__(256)
void corr1d_kernel(const float* __restrict__ in1,
                   const float* __restrict__ in2,
                   float* __restrict__ out) {
    const int c  = blockIdx.y;            // [0,32)
    const int h0 = blockIdx.x * 2;        // [0,128) step 2
    const int t  = threadIdx.x;
    const int r  = t >> 7;                // row within pair: 0/1
    const int w4 = t & (W4 - 1);          // float4 slot in row
    const int h  = h0 + r;

    __shared__ f32x4 s2[2][W4];           // 4 KB: two in2 rows

    const f32x4* in1v = (const f32x4*)in1;
    const f32x4* in2v = (const f32x4*)in2;
    const int rowIdx = (c * H + h) * W4;

    const f32x4 a = in1v[rowIdx + w4];    // lives in registers for all d
    s2[r][w4] = in2v[rowIdx + w4];
    __syncthreads();

    f32x4* outv = (f32x4*)out + (c * D * H + h) * W4 + w4;

    const f32x4 zero4 = (f32x4)(0.f);

    #pragma unroll 1
    for (int j = 0; j < 10; ++j) {        // d = 4j + rr, rr in [0,4)
        const int i0 = w4 - j;
        const f32x4 cur  = (i0     >= 0) ? s2[r][i0]     : zero4;
        const f32x4 prev = (i0 - 1 >= 0) ? s2[r][i0 - 1] : zero4;

        f32x4* o = outv + 4 * j * HW4;

        f32x4 v0;  // rr=0: b = {cur.x, cur.y, cur.z, cur.w}
        v0.x = a.x * cur.x;  v0.y = a.y * cur.y;
        v0.z = a.z * cur.z;  v0.w = a.w * cur.w;
        __builtin_nontemporal_store(v0, o);

        f32x4 v1;  // rr=1: b = {prev.w, cur.x, cur.y, cur.z}
        v1.x = a.x * prev.w; v1.y = a.y * cur.x;
        v1.z = a.z * cur.y;  v1.w = a.w * cur.z;
        __builtin_nontemporal_store(v1, o + HW4);

        f32x4 v2;  // rr=2: b = {prev.z, prev.w, cur.x, cur.y}
        v2.x = a.x * prev.z; v2.y = a.y * prev.w;
        v2.z = a.z * cur.x;  v2.w = a.w * cur.y;
        __builtin_nontemporal_store(v2, o + 2 * HW4);

        f32x4 v3;  // rr=3: b = {prev.y, prev.z, prev.w, cur.x}
        v3.x = a.x * prev.y; v3.y = a.y * prev.z;
        v3.z = a.z * prev.w; v3.w = a.w * cur.x;
        __builtin_nontemporal_store(v3, o + 3 * HW4);
    }

    // d = 40 (j=10, rr=0)
    {
        const int i0 = w4 - 10;
        const f32x4 cur = (i0 >= 0) ? s2[r][i0] : zero4;
        f32x4 v;
        v.x = a.x * cur.x;  v.y = a.y * cur.y;
        v.z = a.z * cur.z;  v.w = a.w * cur.w;
        __builtin_nontemporal_store(v, outv + 40 * HW4);
    }
}

extern "C" void kernel_launch(void* const* d_in, const int* in_sizes, int n_in,
                              void* d_out, int out_size, void* d_ws, size_t ws_size,
                              hipStream_t stream) {
    const float* in1 = (const float*)d_in[0];
    const float* in2 = (const float*)d_in[1];
    float* out = (float*)d_out;

    dim3 block(256);
    dim3 grid(H / 2, C);   // (64, 32) = 2048 workgroups, 4 waves each
    corr1d_kernel<<<grid, block, 0, stream>>>(in1, in2, out);
}